// Round 4
// baseline (280.494 us; speedup 1.0000x reference)
//
#include <hip/hip_runtime.h>
#include <hip/hip_bf16.h>
#include <cstdint>

typedef __bf16 bf16;
typedef __bf16 bf16x8 __attribute__((ext_vector_type(8)));
typedef float f32x4 __attribute__((ext_vector_type(4)));

#define MFMA16(A, B, C) __builtin_amdgcn_mfma_f32_16x16x32_bf16((A), (B), (C), 0, 0, 0)

// async global->LDS 16B DMA; LDS dest must be wave-uniform base + lane*16
__device__ __forceinline__ void async16(const bf16* g, bf16* l) {
    __builtin_amdgcn_global_load_lds(
        (const __attribute__((address_space(1))) void*)g,
        (__attribute__((address_space(3))) void*)l, 16, 0, 0);
}

// ---------------------------------------------------------------------------
// fused f32 -> bf16 convert for all three inputs (one launch)
// ---------------------------------------------------------------------------
__global__ void cvt_all(const float* __restrict__ x, const float* __restrict__ wq,
                        const float* __restrict__ wo, bf16* __restrict__ xb,
                        bf16* __restrict__ wqb, bf16* __restrict__ wob) {
    const int bid = blockIdx.x;
    const float* s;
    bf16* d;
    int off;
    if (bid < 4096)      { s = x;  d = xb;  off = bid; }
    else if (bid < 5632) { s = wq; d = wqb; off = bid - 4096; }
    else                 { s = wo; d = wob; off = bid - 5632; }
    const size_t i = ((size_t)off * 256 + threadIdx.x) * 8;
    const float4 a = *(const float4*)(s + i);
    const float4 b2 = *(const float4*)(s + i + 4);
    bf16x8 r;
    r[0] = (bf16)a.x; r[1] = (bf16)a.y; r[2] = (bf16)a.z; r[3] = (bf16)a.w;
    r[4] = (bf16)b2.x; r[5] = (bf16)b2.y; r[6] = (bf16)b2.z; r[7] = (bf16)b2.w;
    *(bf16x8*)(d + i) = r;
}

// ---------------------------------------------------------------------------
// Phased NT GEMM v2 (m201-style): BM=BN=256, BK=64, 512 thr (8 waves 2x4).
// Per-wave 128x64 out (8x4 16x16 accs), 64 MFMA/K-tile in 4 phases of 16
// (kh x m-half). LDS 128 KiB: per buffer, A and B each stored as two
// contiguous 16 KiB k-half regions [256 rows][4 chunks] so counted vmcnt
// gates exactly one k-half. Swizzle pc = quad ^ (row&3) within each k-half
// (linear gload_lds dest + inverse-swizzled global source + swizzled read).
// Issue 2 loads/phase for tile t+1, order [A-k0, B-k0, A-k1, B-k1];
// vmcnt(4) at phases 0/2 only (worst-case load cover = 3 phases ~460 cyc,
// 3x the round-3 schedule). Barrier each phase; setprio around MFMA.
// MODE 0: QKV scatter epilogue, bf16 (O0=Q, O1=K, O2=V in (B,H,T,64))
// MODE 1: plain row-major f32 store to O0 (ld = N)
// ---------------------------------------------------------------------------
template <int MODE>
__launch_bounds__(512, 2)
__global__ void gemm256(const bf16* __restrict__ A, const bf16* __restrict__ Bm,
                        void* __restrict__ O0, bf16* __restrict__ O1,
                        bf16* __restrict__ O2, int N, int K) {
    // [buf][kh][1024 chunks * 8 elems] per matrix
    __shared__ alignas(16) bf16 As[2 * 2 * 8192];
    __shared__ alignas(16) bf16 Bs[2 * 2 * 8192];

    const int t = threadIdx.x, w = t >> 6, l = t & 63;
    const int quad = l >> 4, l15 = l & 15;
    const int wm = w >> 2, wn = w & 3;

    // XCD-aware block swizzle (nwg % 8 == 0 for both launches)
    const int nwg = gridDim.x;
    const int wg = ((int)blockIdx.x & 7) * (nwg >> 3) + ((int)blockIdx.x >> 3);
    const int NBN = N >> 8;
    const int m0 = (wg / NBN) * 256, n0 = (wg % NBN) * 256;

    const int NT = K >> 6;

    // ---- stage constants: load jj of a k-half: id2 = jj*512+t ----
    // row = id2>>2 (256 rows), pc = id2&3; global chunk (within half) = pc^(row&3)
    int a_src[2], b_src[2], sdst[2];
#pragma unroll
    for (int jj = 0; jj < 2; jj++) {
        const int id2 = jj * 512 + t;
        const int row = id2 >> 2, pc = id2 & 3;
        const int gcoff = (pc ^ (row & 3)) << 3;
        a_src[jj] = (m0 + row) * K + gcoff;
        b_src[jj] = (n0 + row) * K + gcoff;
        sdst[jj] = id2 << 3;
    }

    // ---- read constants ----
    const int pcs = (quad ^ (l15 & 3)) << 3;  // elem offset of phys chunk
    const int arow = wm * 128 + l15;          // + mf*16
    const int brow = wn * 64 + l15;           // + nf*16

    f32x4 acc[8][4] = {};

    // stage lambdas: ktile in 64-elem units
#define STAGE_A(ktile, buf, kh, jj)                                          \
    async16(A + a_src[jj] + (ktile) * 64 + (kh) * 32,                        \
            &As[((((buf) << 1) + (kh)) << 13) + sdst[jj]])
#define STAGE_B(ktile, buf, kh, jj)                                          \
    async16(Bm + b_src[jj] + (ktile) * 64 + (kh) * 32,                       \
            &Bs[((((buf) << 1) + (kh)) << 13) + sdst[jj]])

#define LDA(cb, kh, mf)                                                      \
    (*(const bf16x8*)&As[((((cb) << 1) + (kh)) << 13) +                      \
                         ((arow + (mf) * 16) << 5) + pcs])
#define LDB(cb, kh, nf)                                                      \
    (*(const bf16x8*)&Bs[((((cb) << 1) + (kh)) << 13) +                      \
                         ((brow + (nf) * 16) << 5) + pcs])

    // prologue: stage tile 0, order [A-k0, B-k0, A-k1, B-k1]
    STAGE_A(0, 0, 0, 0); STAGE_A(0, 0, 0, 1);
    STAGE_B(0, 0, 0, 0); STAGE_B(0, 0, 0, 1);
    STAGE_A(0, 0, 1, 0); STAGE_A(0, 0, 1, 1);
    STAGE_B(0, 0, 1, 0); STAGE_B(0, 0, 1, 1);

    for (int tile = 0; tile < NT; ++tile) {
        const int cb = tile & 1, pb = cb ^ 1;
        const bool nl = (tile + 1 < NT);
        const int kn = tile + 1;
        bf16x8 af[4], bfr[4];

        // ---- phase 0: kh=0, mf 0..3 (loads B-k0 frags too) ----
        asm volatile("s_waitcnt vmcnt(4)" ::: "memory");
        __builtin_amdgcn_s_barrier();
        if (nl) { STAGE_A(kn, pb, 0, 0); STAGE_A(kn, pb, 0, 1); }
#pragma unroll
        for (int mf = 0; mf < 4; mf++) af[mf] = LDA(cb, 0, mf);
#pragma unroll
        for (int nf = 0; nf < 4; nf++) bfr[nf] = LDB(cb, 0, nf);
        __builtin_amdgcn_s_setprio(1);
#pragma unroll
        for (int mf = 0; mf < 4; mf++)
#pragma unroll
            for (int nf = 0; nf < 4; nf++)
                acc[mf][nf] = MFMA16(af[mf], bfr[nf], acc[mf][nf]);
        __builtin_amdgcn_s_setprio(0);

        // ---- phase 1: kh=0, mf 4..7 (reuse bfr) ----
        __builtin_amdgcn_s_barrier();
        if (nl) { STAGE_B(kn, pb, 0, 0); STAGE_B(kn, pb, 0, 1); }
#pragma unroll
        for (int mf = 0; mf < 4; mf++) af[mf] = LDA(cb, 0, 4 + mf);
        __builtin_amdgcn_s_setprio(1);
#pragma unroll
        for (int mf = 0; mf < 4; mf++)
#pragma unroll
            for (int nf = 0; nf < 4; nf++)
                acc[4 + mf][nf] = MFMA16(af[mf], bfr[nf], acc[4 + mf][nf]);
        __builtin_amdgcn_s_setprio(0);

        // ---- phase 2: kh=1, mf 0..3 ----
        if (nl) asm volatile("s_waitcnt vmcnt(4)" ::: "memory");
        else    asm volatile("s_waitcnt vmcnt(0)" ::: "memory");
        __builtin_amdgcn_s_barrier();
        if (nl) { STAGE_A(kn, pb, 1, 0); STAGE_A(kn, pb, 1, 1); }
#pragma unroll
        for (int mf = 0; mf < 4; mf++) af[mf] = LDA(cb, 1, mf);
#pragma unroll
        for (int nf = 0; nf < 4; nf++) bfr[nf] = LDB(cb, 1, nf);
        __builtin_amdgcn_s_setprio(1);
#pragma unroll
        for (int mf = 0; mf < 4; mf++)
#pragma unroll
            for (int nf = 0; nf < 4; nf++)
                acc[mf][nf] = MFMA16(af[mf], bfr[nf], acc[mf][nf]);
        __builtin_amdgcn_s_setprio(0);

        // ---- phase 3: kh=1, mf 4..7 ----
        __builtin_amdgcn_s_barrier();
        if (nl) { STAGE_B(kn, pb, 1, 0); STAGE_B(kn, pb, 1, 1); }
#pragma unroll
        for (int mf = 0; mf < 4; mf++) af[mf] = LDA(cb, 1, 4 + mf);
        __builtin_amdgcn_s_setprio(1);
#pragma unroll
        for (int mf = 0; mf < 4; mf++)
#pragma unroll
            for (int nf = 0; nf < 4; nf++)
                acc[4 + mf][nf] = MFMA16(af[mf], bfr[nf], acc[4 + mf][nf]);
        __builtin_amdgcn_s_setprio(0);
    }

    if (MODE == 0) {
        bf16* Q0 = (bf16*)O0;
#pragma unroll
        for (int nf = 0; nf < 4; nf++) {
            const int n = n0 + wn * 64 + nf * 16;
            const int sel = n >> 10;
            const int c = n & 1023;
            const int h = c >> 6;
            const int dd = c & 63;
            bf16* dst = (sel == 0) ? Q0 : ((sel == 1) ? O1 : O2);
#pragma unroll
            for (int mf = 0; mf < 8; mf++) {
#pragma unroll
                for (int r = 0; r < 4; r++) {
                    const int m = m0 + wm * 128 + mf * 16 + quad * 4 + r;
                    const int b = m >> 11, tt = m & 2047;
                    dst[((size_t)(b * 16 + h) * 2048 + tt) * 64 + dd + l15] =
                        (bf16)acc[mf][nf][r];
                }
            }
        }
    } else {
        float* Of = (float*)O0;
#pragma unroll
        for (int mf = 0; mf < 8; mf++) {
#pragma unroll
            for (int nf = 0; nf < 4; nf++) {
#pragma unroll
                for (int r = 0; r < 4; r++) {
                    const int m = m0 + wm * 128 + mf * 16 + quad * 4 + r;
                    const int n = n0 + wn * 64 + nf * 16 + l15;
                    Of[(size_t)m * N + n] = acc[mf][nf][r];
                }
            }
        }
    }
#undef STAGE_A
#undef STAGE_B
#undef LDA
#undef LDB
}

// ---------------------------------------------------------------------------
// V transpose: V (bh, T, 64) -> Vt (bh, 64, T). 64x64 tiles via LDS.
// ---------------------------------------------------------------------------
__launch_bounds__(256, 4)
__global__ void vtrans(const bf16* __restrict__ V, bf16* __restrict__ Vt) {
    __shared__ alignas(16) bf16 Ls[64 * 72];
    const int t = threadIdx.x, bh = blockIdx.y, tt = blockIdx.x;
#pragma unroll
    for (int i = 0; i < 2; i++) {
        const int id = i * 256 + t, r = id >> 3, c = id & 7;
        *(bf16x8*)&Ls[r * 72 + c * 8] =
            *(const bf16x8*)&V[((size_t)bh * 2048 + tt * 64 + r) * 64 + c * 8];
    }
    __syncthreads();
#pragma unroll
    for (int i = 0; i < 2; i++) {
        const int id = i * 256 + t, d = id >> 3, c = id & 7;
        bf16x8 v;
#pragma unroll
        for (int j = 0; j < 8; j++) v[j] = Ls[(c * 8 + j) * 72 + d];
        *(bf16x8*)&Vt[((size_t)bh * 64 + d) * 2048 + tt * 64 + c * 8] = v;
    }
}

// ---------------------------------------------------------------------------
// Causal flash attention, merged-pair K-loop. Block p of (b,h) owns Q-tiles
// qt0=p, qt1=31-p and runs ONE kt-loop 0..qt1: K/V tiles are staged once and
// ka/bv fragments LDS-read once, feeding both halves' MFMAs (half0 active
// while kt<=qt0). S computed transposed (A=K w/ permuted row map, B=Q) so
// each lane's S^T regs are exactly the PV A-frags (in-lane pack, no P LDS).
// Softmax: no reference subtraction (global 2^c cancels in p/sum(p)); raw
// v_exp_f32; li row-sums ride the MFMA pipe (B = ones) in the same C/D row
// layout as O -> no cross-lane reduce. Q pre-scaled by log2(e)/8.
// ---------------------------------------------------------------------------
__launch_bounds__(256, 4)
__global__ void attn_fwd(const bf16* __restrict__ Q, const bf16* __restrict__ Kk,
                         const bf16* __restrict__ Vt, bf16* __restrict__ O) {
    __shared__ alignas(16) bf16 Ks[64 * 72];      // K tile  [kpos][d], ld=72
    __shared__ alignas(16) bf16 Vs[64 * 72];      // Vt tile [d][kpos], ld=72

    const int t = threadIdx.x, w = t >> 6, l = t & 63;
    const int quad = l >> 4, l15 = l & 15;
    const int bh = blockIdx.y, pair = blockIdx.x;
    const int b = bh >> 4, h = bh & 15;
    const int sr = t >> 3, sc = t & 7;

    const bf16* Qbase = Q + (size_t)bh * 2048 * 64;
    const bf16* Kbase = Kk + (size_t)bh * 2048 * 64;
    const bf16* Vbase = Vt + (size_t)bh * 64 * 2048;

    const int qt0 = pair, qt1 = 31 - pair;

    // permuted K-row map: tile nt, lane-m l15 -> local K row
    int kr[4];
#pragma unroll
    for (int nt = 0; nt < 4; nt++)
        kr[nt] = (nt >> 1) * 32 + (l15 >> 2) * 8 + (nt & 1) * 4 + (l15 & 3);

    // Q B-frags for both halves, pre-scaled by log2(e)/8
    bf16x8 aq[2][2];
#pragma unroll
    for (int hf = 0; hf < 2; hf++) {
        const int qrow = (hf ? qt1 : qt0) * 64 + w * 16 + l15;
        aq[hf][0] = *(const bf16x8*)&Qbase[(size_t)qrow * 64 + quad * 8];
        aq[hf][1] = *(const bf16x8*)&Qbase[(size_t)qrow * 64 + 32 + quad * 8];
#pragma unroll
        for (int j = 0; j < 8; j++) {
            aq[hf][0][j] = aq[hf][0][j] * (bf16)0.1803369f;
            aq[hf][1][j] = aq[hf][1][j] * (bf16)0.1803369f;
        }
    }

    // ones B-frag for the li row-sum MFMA
    bf16x8 ones;
#pragma unroll
    for (int j = 0; j < 8; j++) ones[j] = (bf16)1.0f;

    f32x4 liacc[2] = {};
    f32x4 oa[2][4] = {};

    for (int kt = 0; kt <= qt1; kt++) {
        // prefetch K / Vt tiles (rows sr, sr+32)
        bf16x8 rk0 = *(const bf16x8*)&Kbase[(size_t)(kt * 64 + sr) * 64 + sc * 8];
        bf16x8 rk1 = *(const bf16x8*)&Kbase[(size_t)(kt * 64 + sr + 32) * 64 + sc * 8];
        bf16x8 rv0 = *(const bf16x8*)&Vbase[(size_t)sr * 2048 + kt * 64 + sc * 8];
        bf16x8 rv1 = *(const bf16x8*)&Vbase[(size_t)(sr + 32) * 2048 + kt * 64 + sc * 8];
        __syncthreads();  // previous iter's tile reads done
        *(bf16x8*)&Ks[sr * 72 + sc * 8] = rk0;
        *(bf16x8*)&Ks[(sr + 32) * 72 + sc * 8] = rk1;
        *(bf16x8*)&Vs[sr * 72 + sc * 8] = rv0;
        *(bf16x8*)&Vs[(sr + 32) * 72 + sc * 8] = rv1;
        __syncthreads();

        const bool do0 = (kt <= qt0);

        // S^T by nt-pairs; ka frags shared across halves; pack PV A-frags
        bf16x8 ap[2][2];  // [hf][s2]
#pragma unroll
        for (int np = 0; np < 2; np++) {
            bf16x8 ka[2][2];
#pragma unroll
            for (int i = 0; i < 2; i++) {
                ka[i][0] = *(const bf16x8*)&Ks[kr[2 * np + i] * 72 + quad * 8];
                ka[i][1] = *(const bf16x8*)&Ks[kr[2 * np + i] * 72 + 32 + quad * 8];
            }
#pragma unroll
            for (int hf = 0; hf < 2; hf++) {
                if (hf == 0 && !do0) continue;
                const bool diag = (kt == (hf ? qt1 : qt0));
#pragma unroll
                for (int i = 0; i < 2; i++) {
                    f32x4 s = {};
                    s = MFMA16(ka[i][0], aq[hf][0], s);
                    s = MFMA16(ka[i][1], aq[hf][1], s);
                    const int kbase = np * 32 + quad * 8 + i * 4;
#pragma unroll
                    for (int r = 0; r < 4; r++) {
                        float x = s[r];
                        if (diag && (kbase + r) > (w * 16 + l15)) x = -1e30f;
                        ap[hf][np][i * 4 + r] = (bf16)__builtin_amdgcn_exp2f(x);
                    }
                }
            }
        }

        // O += P V : bv frags read once, feed both halves.
#pragma unroll
        for (int s2 = 0; s2 < 2; s2++) {
            if (do0) liacc[0] = MFMA16(ap[0][s2], ones, liacc[0]);
            liacc[1] = MFMA16(ap[1][s2], ones, liacc[1]);
#pragma unroll
            for (int dt = 0; dt < 4; dt++) {
                bf16x8 bv = *(const bf16x8*)&Vs[(dt * 16 + l15) * 72 + s2 * 32 + quad * 8];
                if (do0) oa[0][dt] = MFMA16(ap[0][s2], bv, oa[0][dt]);
                oa[1][dt] = MFMA16(ap[1][s2], bv, oa[1][dt]);
            }
        }
    }

    // epilogue: liacc[hf][r] is already the full row-sum for q-row quad*4+r
#pragma unroll
    for (int hf = 0; hf < 2; hf++) {
        const int qt = hf ? qt1 : qt0;
#pragma unroll
        for (int r = 0; r < 4; r++) {
            const float inv = __builtin_amdgcn_rcpf(liacc[hf][r]);
            const int m = b * 2048 + qt * 64 + w * 16 + quad * 4 + r;
#pragma unroll
            for (int dt = 0; dt < 4; dt++) {
                O[(size_t)m * 1024 + h * 64 + dt * 16 + l15] = (bf16)(oa[hf][dt][r] * inv);
            }
        }
    }
}

// ---------------------------------------------------------------------------
extern "C" void kernel_launch(void* const* d_in, const int* in_sizes, int n_in,
                              void* d_out, int out_size, void* d_ws, size_t ws_size,
                              hipStream_t stream) {
    const float* x = (const float*)d_in[0];     // (8192, 1024) f32
    const float* wqkv = (const float*)d_in[1];  // (3072, 1024) f32
    const float* wo = (const float*)d_in[2];    // (1024, 1024) f32

    const size_t SZ = (size_t)8192 * 1024;
    bf16* xb = (bf16*)d_ws;                 // x bf16; reused as Vt after QKV gemm
    bf16* wqb = xb + SZ;                    // W_qkv bf16
    bf16* wob = wqb + (size_t)3072 * 1024;  // W_o bf16
    bf16* Qw = wob + (size_t)1024 * 1024;
    bf16* Kw = Qw + SZ;
    bf16* Vw = Kw + SZ;                     // V, then reused as attn output
    bf16* Vtw = xb;                         // V transposed (xb dead by then)

    dim3 blk(256);
    cvt_all<<<6144, blk, 0, stream>>>(x, wqkv, wo, xb, wqb, wob);
    gemm256<0><<<dim3(384), dim3(512), 0, stream>>>(xb, wqb, Qw, Kw, Vw, 3072, 1024);
    vtrans<<<dim3(32, 64), blk, 0, stream>>>(Vw, Vtw);
    attn_fwd<<<dim3(16, 64), blk, 0, stream>>>(Qw, Kw, Vtw, Vw);
    gemm256<1><<<dim3(128), dim3(512), 0, stream>>>(Vw, wob, d_out, nullptr, nullptr, 1024, 1024);
}

// Round 5
// 244.220 us; speedup vs baseline: 1.1485x; 1.1485x over previous
//
#include <hip/hip_runtime.h>
#include <hip/hip_bf16.h>
#include <cstdint>

typedef __bf16 bf16;
typedef __bf16 bf16x8 __attribute__((ext_vector_type(8)));
typedef float f32x4 __attribute__((ext_vector_type(4)));

#define MFMA16(A, B, C) __builtin_amdgcn_mfma_f32_16x16x32_bf16((A), (B), (C), 0, 0, 0)

// async global->LDS 16B DMA; LDS dest must be wave-uniform base + lane*16
__device__ __forceinline__ void async16(const bf16* g, bf16* l) {
    __builtin_amdgcn_global_load_lds(
        (const __attribute__((address_space(1))) void*)g,
        (__attribute__((address_space(3))) void*)l, 16, 0, 0);
}

// ---------------------------------------------------------------------------
// fused f32 -> bf16 convert for all three inputs (one launch)
// ---------------------------------------------------------------------------
__global__ void cvt_all(const float* __restrict__ x, const float* __restrict__ wq,
                        const float* __restrict__ wo, bf16* __restrict__ xb,
                        bf16* __restrict__ wqb, bf16* __restrict__ wob) {
    const int bid = blockIdx.x;
    const float* s;
    bf16* d;
    int off;
    if (bid < 4096)      { s = x;  d = xb;  off = bid; }
    else if (bid < 5632) { s = wq; d = wqb; off = bid - 4096; }
    else                 { s = wo; d = wob; off = bid - 5632; }
    const size_t i = ((size_t)off * 256 + threadIdx.x) * 8;
    const float4 a = *(const float4*)(s + i);
    const float4 b2 = *(const float4*)(s + i + 4);
    bf16x8 r;
    r[0] = (bf16)a.x; r[1] = (bf16)a.y; r[2] = (bf16)a.z; r[3] = (bf16)a.w;
    r[4] = (bf16)b2.x; r[5] = (bf16)b2.y; r[6] = (bf16)b2.z; r[7] = (bf16)b2.w;
    *(bf16x8*)(d + i) = r;
}

// ---------------------------------------------------------------------------
// NT GEMM, pure bf16, async global_load_lds staging (m97 structure).
// 128x128 tile, BK=64, 256 threads (4 waves, 2x2 wave grid, 4x4 16x16 accs).
// XCD-aware bijective block swizzle (T1): each XCD gets a contiguous chunk
// of n-fastest tile order so blocks sharing an A m-panel share an L2.
// MODE 0: QKV scatter epilogue, bf16 out (O0=Q, O1=K, O2=V in (B,H,T,64))
// MODE 1: plain row-major f32 store to O0 (ld = N)
// ---------------------------------------------------------------------------
template <int MODE>
__launch_bounds__(256, 3)
__global__ void gemm_nt(const bf16* __restrict__ A, const bf16* __restrict__ Bm,
                        void* __restrict__ O0, bf16* __restrict__ O1,
                        bf16* __restrict__ O2, int N, int K) {
    __shared__ alignas(16) bf16 As[128 * 64];
    __shared__ alignas(16) bf16 Bs[128 * 64];

    const int t = threadIdx.x;
    const int w = t >> 6, l = t & 63, quad = l >> 4, l15 = l & 15;
    const int wm = w & 1, wn = w >> 1;

    // XCD swizzle (nwg % 8 == 0 for both launches: 1536, 512)
    const int gx = (int)gridDim.x;
    const int nwg = gx * (int)gridDim.y;
    const int wg0 = (int)blockIdx.y * gx + (int)blockIdx.x;
    const int wg = (wg0 & 7) * (nwg >> 3) + (wg0 >> 3);
    const int m0 = (wg / gx) * 128, n0 = (wg % gx) * 128;

    f32x4 acc[4][4] = {};

    const int srow = t >> 3, sch = t & 7;
    const bf16* ga = A + (size_t)(m0 + srow) * K + sch * 8;
    const bf16* gb = Bm + (size_t)(n0 + srow) * K + sch * 8;

    for (int kt = 0; kt < K; kt += 64) {
        __syncthreads();
#pragma unroll
        for (int i = 0; i < 4; i++) {
            async16(ga + (size_t)i * 32 * K + kt, &As[(i * 256 + t) * 8]);
            async16(gb + (size_t)i * 32 * K + kt, &Bs[(i * 256 + t) * 8]);
        }
        __syncthreads();

#pragma unroll
        for (int s = 0; s < 2; s++) {
            bf16x8 af[4], bfr[4];
#pragma unroll
            for (int im = 0; im < 4; im++)
                af[im] = *(const bf16x8*)&As[(wm * 64 + im * 16 + l15) * 64 + s * 32 + quad * 8];
#pragma unroll
            for (int in = 0; in < 4; in++)
                bfr[in] = *(const bf16x8*)&Bs[(wn * 64 + in * 16 + l15) * 64 + s * 32 + quad * 8];
#pragma unroll
            for (int im = 0; im < 4; im++)
#pragma unroll
                for (int in = 0; in < 4; in++)
                    acc[im][in] = MFMA16(af[im], bfr[in], acc[im][in]);
        }
    }

    if (MODE == 0) {
        bf16* Q0 = (bf16*)O0;
#pragma unroll
        for (int in = 0; in < 4; in++) {
            const int n = n0 + wn * 64 + in * 16;
            const int sel = n >> 10;
            const int c = n & 1023;
            const int h = c >> 6;
            const int dd = c & 63;
            bf16* dst = (sel == 0) ? Q0 : ((sel == 1) ? O1 : O2);
#pragma unroll
            for (int im = 0; im < 4; im++) {
#pragma unroll
                for (int r = 0; r < 4; r++) {
                    const int m = m0 + wm * 64 + im * 16 + quad * 4 + r;
                    const int b = m >> 11, tt = m & 2047;
                    dst[((size_t)(b * 16 + h) * 2048 + tt) * 64 + dd + l15] =
                        (bf16)acc[im][in][r];
                }
            }
        }
    } else {
        float* Of = (float*)O0;
#pragma unroll
        for (int im = 0; im < 4; im++) {
#pragma unroll
            for (int in = 0; in < 4; in++) {
#pragma unroll
                for (int r = 0; r < 4; r++) {
                    const int m = m0 + wm * 64 + im * 16 + quad * 4 + r;
                    const int n = n0 + wn * 64 + in * 16 + l15;
                    Of[(size_t)m * N + n] = acc[im][in][r];
                }
            }
        }
    }
}

// ---------------------------------------------------------------------------
// V transpose: V (bh, T, 64) -> Vt (bh, 64, T). 64x64 tiles via LDS.
// ---------------------------------------------------------------------------
__launch_bounds__(256, 4)
__global__ void vtrans(const bf16* __restrict__ V, bf16* __restrict__ Vt) {
    __shared__ alignas(16) bf16 Ls[64 * 72];
    const int t = threadIdx.x, bh = blockIdx.y, tt = blockIdx.x;
#pragma unroll
    for (int i = 0; i < 2; i++) {
        const int id = i * 256 + t, r = id >> 3, c = id & 7;
        *(bf16x8*)&Ls[r * 72 + c * 8] =
            *(const bf16x8*)&V[((size_t)bh * 2048 + tt * 64 + r) * 64 + c * 8];
    }
    __syncthreads();
#pragma unroll
    for (int i = 0; i < 2; i++) {
        const int id = i * 256 + t, d = id >> 3, c = id & 7;
        bf16x8 v;
#pragma unroll
        for (int j = 0; j < 8; j++) v[j] = Ls[(c * 8 + j) * 72 + d];
        *(bf16x8*)&Vt[((size_t)bh * 64 + d) * 2048 + tt * 64 + c * 8] = v;
    }
}

// ---------------------------------------------------------------------------
// Causal flash attention, merged-pair K-loop. Block p of (b,h) owns Q-tiles
// qt0=p, qt1=31-p and runs ONE kt-loop 0..qt1: K/V tiles are staged once and
// ka/bv fragments LDS-read once, feeding both halves' MFMAs (half0 active
// while kt<=qt0). S computed transposed (A=K w/ permuted row map, B=Q) so
// each lane's S^T regs are exactly the PV A-frags (in-lane pack, no P LDS).
// Softmax: no reference subtraction (global 2^c cancels in p/sum(p)); raw
// v_exp_f32; li row-sums ride the MFMA pipe (B = ones) in the same C/D row
// layout as O -> no cross-lane reduce. Q pre-scaled by log2(e)/8.
// T14 async-STAGE: tile kt+1's global loads are issued BEFORE compute of
// tile kt, so HBM/L2 latency hides under the MFMA phase; the ds_write that
// consumes them (next iter, after a barrier) carries the vmcnt dependency.
// ---------------------------------------------------------------------------
__launch_bounds__(256, 4)
__global__ void attn_fwd(const bf16* __restrict__ Q, const bf16* __restrict__ Kk,
                         const bf16* __restrict__ Vt, bf16* __restrict__ O) {
    __shared__ alignas(16) bf16 Ks[64 * 72];      // K tile  [kpos][d], ld=72
    __shared__ alignas(16) bf16 Vs[64 * 72];      // Vt tile [d][kpos], ld=72

    const int t = threadIdx.x, w = t >> 6, l = t & 63;
    const int quad = l >> 4, l15 = l & 15;
    const int bh = blockIdx.y, pair = blockIdx.x;
    const int b = bh >> 4, h = bh & 15;
    const int sr = t >> 3, sc = t & 7;

    const bf16* Qbase = Q + (size_t)bh * 2048 * 64;
    const bf16* Kbase = Kk + (size_t)bh * 2048 * 64;
    const bf16* Vbase = Vt + (size_t)bh * 64 * 2048;

    const int qt0 = pair, qt1 = 31 - pair;

    // permuted K-row map: tile nt, lane-m l15 -> local K row
    int kr[4];
#pragma unroll
    for (int nt = 0; nt < 4; nt++)
        kr[nt] = (nt >> 1) * 32 + (l15 >> 2) * 8 + (nt & 1) * 4 + (l15 & 3);

    // Q B-frags for both halves, pre-scaled by log2(e)/8
    bf16x8 aq[2][2];
#pragma unroll
    for (int hf = 0; hf < 2; hf++) {
        const int qrow = (hf ? qt1 : qt0) * 64 + w * 16 + l15;
        aq[hf][0] = *(const bf16x8*)&Qbase[(size_t)qrow * 64 + quad * 8];
        aq[hf][1] = *(const bf16x8*)&Qbase[(size_t)qrow * 64 + 32 + quad * 8];
#pragma unroll
        for (int j = 0; j < 8; j++) {
            aq[hf][0][j] = aq[hf][0][j] * (bf16)0.1803369f;
            aq[hf][1][j] = aq[hf][1][j] * (bf16)0.1803369f;
        }
    }

    // ones B-frag for the li row-sum MFMA
    bf16x8 ones;
#pragma unroll
    for (int j = 0; j < 8; j++) ones[j] = (bf16)1.0f;

    f32x4 liacc[2] = {};
    f32x4 oa[2][4] = {};

    // prologue: load tile 0 into registers
    bf16x8 rk0 = *(const bf16x8*)&Kbase[(size_t)sr * 64 + sc * 8];
    bf16x8 rk1 = *(const bf16x8*)&Kbase[(size_t)(sr + 32) * 64 + sc * 8];
    bf16x8 rv0 = *(const bf16x8*)&Vbase[(size_t)sr * 2048 + sc * 8];
    bf16x8 rv1 = *(const bf16x8*)&Vbase[(size_t)(sr + 32) * 2048 + sc * 8];

    for (int kt = 0; kt <= qt1; kt++) {
        __syncthreads();  // previous iter's tile reads done
        *(bf16x8*)&Ks[sr * 72 + sc * 8] = rk0;
        *(bf16x8*)&Ks[(sr + 32) * 72 + sc * 8] = rk1;
        *(bf16x8*)&Vs[sr * 72 + sc * 8] = rv0;
        *(bf16x8*)&Vs[(sr + 32) * 72 + sc * 8] = rv1;
        __syncthreads();

        // T14: issue next tile's loads now; latency hides under compute below
        if (kt < qt1) {
            const int kn = kt + 1;
            rk0 = *(const bf16x8*)&Kbase[(size_t)(kn * 64 + sr) * 64 + sc * 8];
            rk1 = *(const bf16x8*)&Kbase[(size_t)(kn * 64 + sr + 32) * 64 + sc * 8];
            rv0 = *(const bf16x8*)&Vbase[(size_t)sr * 2048 + kn * 64 + sc * 8];
            rv1 = *(const bf16x8*)&Vbase[(size_t)(sr + 32) * 2048 + kn * 64 + sc * 8];
        }

        const bool do0 = (kt <= qt0);

        // S^T by nt-pairs; ka frags shared across halves; pack PV A-frags
        bf16x8 ap[2][2];  // [hf][s2]
#pragma unroll
        for (int np = 0; np < 2; np++) {
            bf16x8 ka[2][2];
#pragma unroll
            for (int i = 0; i < 2; i++) {
                ka[i][0] = *(const bf16x8*)&Ks[kr[2 * np + i] * 72 + quad * 8];
                ka[i][1] = *(const bf16x8*)&Ks[kr[2 * np + i] * 72 + 32 + quad * 8];
            }
#pragma unroll
            for (int hf = 0; hf < 2; hf++) {
                if (hf == 0 && !do0) continue;
                const bool diag = (kt == (hf ? qt1 : qt0));
#pragma unroll
                for (int i = 0; i < 2; i++) {
                    f32x4 s = {};
                    s = MFMA16(ka[i][0], aq[hf][0], s);
                    s = MFMA16(ka[i][1], aq[hf][1], s);
                    const int kbase = np * 32 + quad * 8 + i * 4;
#pragma unroll
                    for (int r = 0; r < 4; r++) {
                        float x = s[r];
                        if (diag && (kbase + r) > (w * 16 + l15)) x = -1e30f;
                        ap[hf][np][i * 4 + r] = (bf16)__builtin_amdgcn_exp2f(x);
                    }
                }
            }
        }

        // O += P V : bv frags read once, feed both halves.
#pragma unroll
        for (int s2 = 0; s2 < 2; s2++) {
            if (do0) liacc[0] = MFMA16(ap[0][s2], ones, liacc[0]);
            liacc[1] = MFMA16(ap[1][s2], ones, liacc[1]);
#pragma unroll
            for (int dt = 0; dt < 4; dt++) {
                bf16x8 bv = *(const bf16x8*)&Vs[(dt * 16 + l15) * 72 + s2 * 32 + quad * 8];
                if (do0) oa[0][dt] = MFMA16(ap[0][s2], bv, oa[0][dt]);
                oa[1][dt] = MFMA16(ap[1][s2], bv, oa[1][dt]);
            }
        }
    }

    // epilogue: liacc[hf][r] is already the full row-sum for q-row quad*4+r
#pragma unroll
    for (int hf = 0; hf < 2; hf++) {
        const int qt = hf ? qt1 : qt0;
#pragma unroll
        for (int r = 0; r < 4; r++) {
            const float inv = __builtin_amdgcn_rcpf(liacc[hf][r]);
            const int m = b * 2048 + qt * 64 + w * 16 + quad * 4 + r;
#pragma unroll
            for (int dt = 0; dt < 4; dt++) {
                O[(size_t)m * 1024 + h * 64 + dt * 16 + l15] = (bf16)(oa[hf][dt][r] * inv);
            }
        }
    }
}

// ---------------------------------------------------------------------------
extern "C" void kernel_launch(void* const* d_in, const int* in_sizes, int n_in,
                              void* d_out, int out_size, void* d_ws, size_t ws_size,
                              hipStream_t stream) {
    const float* x = (const float*)d_in[0];     // (8192, 1024) f32
    const float* wqkv = (const float*)d_in[1];  // (3072, 1024) f32
    const float* wo = (const float*)d_in[2];    // (1024, 1024) f32

    const size_t SZ = (size_t)8192 * 1024;
    bf16* xb = (bf16*)d_ws;                 // x bf16; reused as Vt after QKV gemm
    bf16* wqb = xb + SZ;                    // W_qkv bf16
    bf16* wob = wqb + (size_t)3072 * 1024;  // W_o bf16
    bf16* Qw = wob + (size_t)1024 * 1024;
    bf16* Kw = Qw + SZ;
    bf16* Vw = Kw + SZ;                     // V, then reused as attn output
    bf16* Vtw = xb;                         // V transposed (xb dead by then)

    dim3 blk(256);
    cvt_all<<<6144, blk, 0, stream>>>(x, wqkv, wo, xb, wqb, wob);
    gemm_nt<0><<<dim3(24, 64), blk, 0, stream>>>(xb, wqb, Qw, Kw, Vw, 3072, 1024);
    vtrans<<<dim3(32, 64), blk, 0, stream>>>(Vw, Vtw);
    attn_fwd<<<dim3(16, 64), blk, 0, stream>>>(Qw, Kw, Vtw, Vw);
    gemm_nt<1><<<dim3(8, 64), blk, 0, stream>>>(Vw, wob, d_out, nullptr, nullptr, 1024, 1024);
}